// Round 8
// baseline (1376.821 us; speedup 1.0000x reference)
//
#include <hip/hip_runtime.h>
#include <cmath>

#define T_SEQ 2048
#define NH    16
#define HD    64
#define DM    1024
#define BATCH 4

typedef __attribute__((ext_vector_type(8))) short bf16x8;
typedef __attribute__((ext_vector_type(4))) float f32x4;
typedef unsigned short ushort_t;

__device__ __forceinline__ unsigned short f2bf(float x) {   // rne fp32->bf16
    union { float f; unsigned u; } v; v.f = x;
    unsigned r = v.u + 0x7fffu + ((v.u >> 16) & 1u);
    return (unsigned short)(r >> 16);
}
__device__ __forceinline__ float bf2f(unsigned short h) {
    union { unsigned u; float f; } v; v.u = ((unsigned)h) << 16;
    return v.f;
}
__device__ __forceinline__ unsigned fbits(float x) {
    union { float f; unsigned u; } v; v.f = x; return v.u;
}
__device__ __forceinline__ float bitsf(unsigned x) {
    union { unsigned u; float f; } v; v.u = x; return v.f;
}

// async global->LDS DMA, 16 B per lane (verified working R7).
__device__ __forceinline__ void dma16(const void* g, const void* l) {
    __builtin_amdgcn_global_load_lds(
        (const __attribute__((address_space(1))) unsigned int*)(unsigned long long)g,
        (__attribute__((address_space(3))) unsigned int*)(unsigned int)(unsigned long long)l,
        16, 0, 0);
}

// -------------------------------------------------------------------------
// Kernel 1: mask prep (unchanged).
// -------------------------------------------------------------------------
__global__ void maskprep_kernel(const int* __restrict__ pad, float* __restrict__ valid)
{
    __shared__ int sall[256];
    const int b = blockIdx.x;
    const int t = threadIdx.x;
    int allp = 1;
    for (int i = t; i < T_SEQ; i += 256) allp &= (pad[b*T_SEQ + i] != 0) ? 1 : 0;
    sall[t] = allp;
    __syncthreads();
    for (int s = 128; s > 0; s >>= 1) {
        if (t < s) sall[t] &= sall[t + s];
        __syncthreads();
    }
    const int ap = sall[0];
    for (int i = t; i < T_SEQ; i += 256) {
        const int p = (pad[b*T_SEQ + i] != 0) ? 1 : 0;
        valid[b*T_SEQ + i] = (p && !ap) ? 0.0f : 1.0f;
    }
}

// -------------------------------------------------------------------------
// Kernel 2: weight transpose+split (unchanged). W[K][N] -> Th/Tl[N][K].
// -------------------------------------------------------------------------
__global__ __launch_bounds__(256)
void transpose_split_kernel(const float* __restrict__ W,
                            ushort_t* __restrict__ Th, ushort_t* __restrict__ Tl,
                            int K, int N)
{
    __shared__ float T[64][68];
    const int tid = threadIdx.x;
    const int n0 = blockIdx.x * 64;
    const int k0 = blockIdx.y * 64;
#pragma unroll
    for (int i = 0; i < 4; ++i) {
        const int kr = (tid >> 4) + i*16;
        const int nc = (tid & 15) * 4;
        const float4 v = *(const float4*)&W[(size_t)(k0 + kr)*N + n0 + nc];
        T[nc+0][kr] = v.x; T[nc+1][kr] = v.y; T[nc+2][kr] = v.z; T[nc+3][kr] = v.w;
    }
    __syncthreads();
#pragma unroll
    for (int i = 0; i < 4; ++i) {
        const int nr = (tid >> 4) + i*16;
        const int kc = (tid & 15) * 4;
        ushort_t h[4], l[4];
#pragma unroll
        for (int j = 0; j < 4; ++j) {
            const float x = T[nr][kc + j];
            h[j] = f2bf(x);
            l[j] = f2bf(x - bf2f(h[j]));
        }
        const size_t off = (size_t)(n0 + nr)*K + k0 + kc;
        *(short4*)&Th[off] = make_short4(h[0], h[1], h[2], h[3]);
        *(short4*)&Tl[off] = make_short4(l[0], l[1], l[2], l[3]);
    }
}

// -------------------------------------------------------------------------
// Kernel 2b: row-major fp32 -> bf16 hi/lo split (unchanged).
// -------------------------------------------------------------------------
__global__ __launch_bounds__(256)
void split_kernel(const float* __restrict__ X,
                  ushort_t* __restrict__ H, ushort_t* __restrict__ L)
{
    const int i = blockIdx.x * 256 + threadIdx.x;     // float4 index
    const float4 v = ((const float4*)X)[i];
    const float x[4] = {v.x, v.y, v.z, v.w};
    ushort_t h[4], l[4];
#pragma unroll
    for (int j = 0; j < 4; ++j) {
        const unsigned u = fbits(x[j]);
        h[j] = (ushort_t)(u >> 16);
        l[j] = f2bf(x[j] - bitsf(u & 0xffff0000u));
    }
    *(short4*)&H[(size_t)i*4] = make_short4(h[0], h[1], h[2], h[3]);
    *(short4*)&L[(size_t)i*4] = make_short4(l[0], l[1], l[2], l[3]);
}

// -------------------------------------------------------------------------
// Kernel 3/5: split-bf16 MFMA GEMM, 128x128xBK32, global_load_lds staging.
// R8 change: the 48-MFMA block is split into 3 phases so at most ~12
// fragments are live at once (R7 held all 16 + acc -> allocator spilled
// the frag set to scratch every iter = 3.2 GB HBM writes, the measured
// WRITE_SIZE). Phases: [read afh,bfh; ah*bh] [read bfl; ah*bl]
// [read afl; barrier; DMA kt+1; al*bh (covers DMA)].
// -------------------------------------------------------------------------
template<int EPI>
__global__ __launch_bounds__(256, 2)
void mfma_gemm_kernel(const ushort_t* __restrict__ Ath, const ushort_t* __restrict__ Atl,
                      const ushort_t* __restrict__ BTh, const ushort_t* __restrict__ BTl,
                      const float* __restrict__ bias,
                      float* __restrict__ O0,
                      ushort_t* __restrict__ Qhi, ushort_t* __restrict__ Qlo,
                      ushort_t* __restrict__ Khi, ushort_t* __restrict__ Klo,
                      ushort_t* __restrict__ Vthi, ushort_t* __restrict__ Vtlo,
                      int M, int N, int K)
{
    __shared__ __align__(16) char smem[34816];   // 32 KB tiles / 34 KB epi union
    char* smA  = smem;            // Ah: 8 KB
    char* smAl = smem + 8192;     // Al
    char* smBh = smem + 16384;    // Bh
    char* smBl = smem + 24576;    // Bl

    const int tid  = threadIdx.x;
    const int w    = tid >> 6;
    const int ln   = tid & 63;
    const int lx   = ln & 15;
    const int quad = ln >> 4;
    const int mw   = (w >> 1) * 64;
    const int nw   = (w & 1) * 64;
    const int m0   = blockIdx.y * 128;
    const int n0   = blockIdx.x * 128;

    // DMA geometry (verified R7): instr j covers row (w*32 + j*16 + ln/4),
    // 16B chunk (ln&3).
    const int drow  = w*32 + (ln >> 2);
    const size_t ga0 = (size_t)(m0 + drow)*K + (ln & 3)*8;
    const size_t gb0 = (size_t)(n0 + drow)*K + (ln & 3)*8;
    const int lds0   = (w*128 + ln)*16;

#define ISSUE_DMA(kk) do {                                               \
        dma16(Ath + ga0 + (kk),        smA  + lds0);                     \
        dma16(Ath + ga0 + 16*K + (kk), smA  + lds0 + 1024);              \
        dma16(Atl + ga0 + (kk),        smAl + lds0);                     \
        dma16(Atl + ga0 + 16*K + (kk), smAl + lds0 + 1024);              \
        dma16(BTh + gb0 + (kk),        smBh + lds0);                     \
        dma16(BTh + gb0 + 16*K + (kk), smBh + lds0 + 1024);              \
        dma16(BTl + gb0 + (kk),        smBl + lds0);                     \
        dma16(BTl + gb0 + 16*K + (kk), smBl + lds0 + 1024);              \
    } while (0)

    f32x4 acc[4][4];
#pragma unroll
    for (int mt = 0; mt < 4; ++mt)
#pragma unroll
        for (int nt = 0; nt < 4; ++nt) acc[mt][nt] = (f32x4){0.f,0.f,0.f,0.f};

    ISSUE_DMA(0);

    for (int kk = 0; kk < K; kk += 32) {
        __syncthreads();                       // DMA for tile kk landed

        // ---- phase 1: ah * bh ----
        bf16x8 afh[4], bfh[4];
#pragma unroll
        for (int mt = 0; mt < 4; ++mt)
            afh[mt] = *(const bf16x8*)(smA + (mw + mt*16 + lx)*64 + quad*16);
#pragma unroll
        for (int nt = 0; nt < 4; ++nt)
            bfh[nt] = *(const bf16x8*)(smBh + (nw + nt*16 + lx)*64 + quad*16);
#pragma unroll
        for (int mt = 0; mt < 4; ++mt)
#pragma unroll
            for (int nt = 0; nt < 4; ++nt)
                acc[mt][nt] = __builtin_amdgcn_mfma_f32_16x16x32_bf16(afh[mt], bfh[nt], acc[mt][nt], 0, 0, 0);

        // ---- phase 2: ah * bl ----
        {
            bf16x8 bfl[4];
#pragma unroll
            for (int nt = 0; nt < 4; ++nt)
                bfl[nt] = *(const bf16x8*)(smBl + (nw + nt*16 + lx)*64 + quad*16);
#pragma unroll
            for (int mt = 0; mt < 4; ++mt)
#pragma unroll
                for (int nt = 0; nt < 4; ++nt)
                    acc[mt][nt] = __builtin_amdgcn_mfma_f32_16x16x32_bf16(afh[mt], bfl[nt], acc[mt][nt], 0, 0, 0);
        }

        // ---- phase 3: al * bh (reads done -> barrier -> DMA kt+1 -> MFMA) ----
        {
            bf16x8 afl[4];
#pragma unroll
            for (int mt = 0; mt < 4; ++mt)
                afl[mt] = *(const bf16x8*)(smAl + (mw + mt*16 + lx)*64 + quad*16);
            __syncthreads();                   // all LDS reads complete
            if (kk + 32 < K) ISSUE_DMA(kk + 32);
#pragma unroll
            for (int mt = 0; mt < 4; ++mt)
#pragma unroll
                for (int nt = 0; nt < 4; ++nt)
                    acc[mt][nt] = __builtin_amdgcn_mfma_f32_16x16x32_bf16(afl[mt], bfh[nt], acc[mt][nt], 0, 0, 0);
        }
    }
#undef ISSUE_DMA

    // ---------------- epilogue (R6/R7 logic, verified) ----------------
    if (EPI == 0) {
#pragma unroll
        for (int nt = 0; nt < 4; ++nt) {
            const int n = n0 + nw + nt*16 + lx;
#pragma unroll
            for (int mt = 0; mt < 4; ++mt)
#pragma unroll
                for (int r = 0; r < 4; ++r) {
                    const int m = m0 + mw + mt*16 + quad*4 + r;
                    O0[(size_t)m*N + n] = acc[mt][nt][r] + bias[n];
                }
        }
    } else {
        const int which = n0 >> 10;           // block-uniform: 0=q 1=k 2=v
        const int hbase = (n0 & 1023) >> 6;
        const int b     = m0 >> 11;
        const int t0    = m0 & 2047;
        float* Ct = (float*)smem;             // Q/K: [64][132]; V: [128][68]
        const float ssign = (lx & 1) ? 1.0f : -1.0f;

        for (int mhalf = 0; mhalf < 2; ++mhalf) {
            __syncthreads();
            if (mw == mhalf*64) {
                if (which < 2) {
#pragma unroll
                    for (int nt = 0; nt < 4; ++nt) {
                        const int nl = nw + nt*16 + lx;
                        const int d  = nl & 63;
                        const float bn = bias[n0 + nl];
                        const float freq = expf(-(float)(d >> 1) * 0.28782313662425575f);
#pragma unroll
                        for (int mt = 0; mt < 4; ++mt)
#pragma unroll
                            for (int r = 0; r < 4; ++r) {
                                const int ml = mt*16 + quad*4 + r;
                                const int t  = t0 + mhalf*64 + ml;
                                float res = acc[mt][nt][r] + bn;
                                const float ang = (float)t * freq;
                                const float sn = sinf(ang), cs = cosf(ang);
                                const float prt = __shfl_xor(res, 1);
                                res = res*cs + ssign*prt*sn;
                                if (which == 0) res *= 0.125f;
                                Ct[ml*132 + nl] = res;
                            }
                    }
                } else {
#pragma unroll
                    for (int nt = 0; nt < 4; ++nt) {
                        const int nl = nw + nt*16 + lx;
                        const float bn = bias[n0 + nl];
#pragma unroll
                        for (int mt = 0; mt < 4; ++mt)
#pragma unroll
                            for (int r = 0; r < 4; ++r) {
                                const int ml = mt*16 + quad*4 + r;
                                Ct[nl*68 + ml] = acc[mt][nt][r] + bn;
                            }
                    }
                }
            }
            __syncthreads();
            if (which < 2) {
                ushort_t* dH = which ? Khi : Qhi;
                ushort_t* dL = which ? Klo : Qlo;
#pragma unroll
                for (int ui = 0; ui < 4; ++ui) {
                    const int u  = w*4 + ui;
                    const int hl = u >> 3, titer = u & 7;
                    const int tl = titer*8 + (ln >> 3);
                    const int dg = (ln & 7) * 8;
                    const float* src = &Ct[tl*132 + hl*64 + dg];
                    float v[8];
                    *(f32x4*)&v[0] = *(const f32x4*)src;
                    *(f32x4*)&v[4] = *(const f32x4*)(src + 4);
                    bf16x8 h8, l8;
#pragma unroll
                    for (int j = 0; j < 8; ++j) {
                        const unsigned u32 = fbits(v[j]);
                        h8[j] = (short)(u32 >> 16);
                        l8[j] = (short)f2bf(v[j] - bitsf(u32 & 0xffff0000u));
                    }
                    const int t  = t0 + mhalf*64 + tl;
                    const int bh = b*NH + hbase + hl;
                    const size_t off = (((size_t)bh)*T_SEQ + t)*64 + dg;
                    *(bf16x8*)&dH[off] = h8;
                    *(bf16x8*)&dL[off] = l8;
                }
            } else {
#pragma unroll
                for (int ui = 0; ui < 4; ++ui) {
                    const int u  = w*4 + ui;
                    const int nr = u*8 + (ln >> 3);
                    const int d  = nr & 63, hl = nr >> 6;
                    const int tg = (ln & 7) * 8;
                    const float* src = &Ct[nr*68 + tg];
                    float v[8];
                    *(f32x4*)&v[0] = *(const f32x4*)src;
                    *(f32x4*)&v[4] = *(const f32x4*)(src + 4);
                    bf16x8 h8, l8;
#pragma unroll
                    for (int j = 0; j < 8; ++j) {
                        const unsigned u32 = fbits(v[j]);
                        h8[j] = (short)(u32 >> 16);
                        l8[j] = (short)f2bf(v[j] - bitsf(u32 & 0xffff0000u));
                    }
                    const int bh = b*NH + hbase + hl;
                    const size_t off = (((size_t)bh)*HD + d)*T_SEQ + t0 + mhalf*64 + tg;
                    *(bf16x8*)&Vthi[off] = h8;
                    *(bf16x8*)&Vtlo[off] = l8;
                }
            }
        }
    }
}

// -------------------------------------------------------------------------
// Kernel 4: flash attention (unchanged — verified).
// -------------------------------------------------------------------------
__global__ __launch_bounds__(256, 2)
void attn_mfma_kernel(const ushort_t* __restrict__ Qhi, const ushort_t* __restrict__ Qlo,
                      const ushort_t* __restrict__ Khi, const ushort_t* __restrict__ Klo,
                      const ushort_t* __restrict__ Vthi, const ushort_t* __restrict__ Vtlo,
                      const float* __restrict__ valid, float* __restrict__ O)
{
    __shared__ ushort_t KH[64*64];
    __shared__ ushort_t KL[64*64];
    __shared__ ushort_t VH[64*64];
    __shared__ ushort_t VL[64*64];
    __shared__ float Pb[4][16][68];

    const int tid  = threadIdx.x;
    const int w    = tid >> 6;
    const int ln   = tid & 63;
    const int lx   = ln & 15;
    const int quad = ln >> 4;

    const int id = blockIdx.x;
    const int qt = (id >> 3) & 31;
    const int bh = ((id >> 8) << 3) | (id & 7);
    const int b  = bh >> 4;
    const int h  = bh & 15;
    const int qrow0 = qt*64 + w*16;

    bf16x8 qh[2], ql[2];
    {
        const size_t qoff = (((size_t)bh)*T_SEQ + qrow0 + lx)*HD + quad*8;
        qh[0] = *(const bf16x8*)&Qhi[qoff];
        qh[1] = *(const bf16x8*)&Qhi[qoff + 32];
        ql[0] = *(const bf16x8*)&Qlo[qoff];
        ql[1] = *(const bf16x8*)&Qlo[qoff + 32];
    }

    const int srow0 = w*16 + (ln >> 3);
    const int sch   = ln & 7;
    const size_t kg0 = ((size_t)bh*T_SEQ + srow0)*HD + sch*8;
    const size_t vg0 = ((size_t)bh*HD + srow0)*T_SEQ + sch*8;
    int lw[2];
#pragma unroll
    for (int p = 0; p < 2; ++p) {
        const int r = srow0 + p*8;
        lw[p] = r*64 + ((sch ^ (r & 7)) * 8);
    }

    const float* vrow = valid + (size_t)b*T_SEQ + lx;

    f32x4 o[4];
#pragma unroll
    for (int nt = 0; nt < 4; ++nt) o[nt] = (f32x4){0.f, 0.f, 0.f, 0.f};
    float mrow[4] = {-INFINITY, -INFINITY, -INFINITY, -INFINITY};
    float lrow[4] = {0.f, 0.f, 0.f, 0.f};

    bf16x8 rkh[2], rkl[2], rvh[2], rvl[2];
#pragma unroll
    for (int p = 0; p < 2; ++p) {
        rkh[p] = *(const bf16x8*)&Khi [kg0 + p*8*HD];
        rkl[p] = *(const bf16x8*)&Klo [kg0 + p*8*HD];
        rvh[p] = *(const bf16x8*)&Vthi[vg0 + p*8*T_SEQ];
        rvl[p] = *(const bf16x8*)&Vtlo[vg0 + p*8*T_SEQ];
    }
#pragma unroll
    for (int p = 0; p < 2; ++p) {
        *(bf16x8*)&KH[lw[p]] = rkh[p];
        *(bf16x8*)&KL[lw[p]] = rkl[p];
        *(bf16x8*)&VH[lw[p]] = rvh[p];
        *(bf16x8*)&VL[lw[p]] = rvl[p];
    }
    __syncthreads();

    for (int kt = 0; kt < T_SEQ/64; ++kt) {
        const int ktn = (kt+1 < T_SEQ/64) ? kt+1 : kt;
#pragma unroll
        for (int p = 0; p < 2; ++p) {
            rkh[p] = *(const bf16x8*)&Khi [kg0 + (size_t)ktn*64*HD + p*8*HD];
            rkl[p] = *(const bf16x8*)&Klo [kg0 + (size_t)ktn*64*HD + p*8*HD];
            rvh[p] = *(const bf16x8*)&Vthi[vg0 + ktn*64 + p*8*T_SEQ];
            rvl[p] = *(const bf16x8*)&Vtlo[vg0 + ktn*64 + p*8*T_SEQ];
        }
        float mk[4];
#pragma unroll
        for (int nt = 0; nt < 4; ++nt) mk[nt] = vrow[kt*64 + nt*16];

        f32x4 s[4];
#pragma unroll
        for (int nt = 0; nt < 4; ++nt) {
            const int row = nt*16 + lx;
            const int base = row*64;
            const int sw = lx & 7;
            const int c0 = ((0*4 + quad) ^ sw) * 8;
            const int c1 = ((1*4 + quad) ^ sw) * 8;
            const bf16x8 kh0 = *(const bf16x8*)&KH[base + c0];
            const bf16x8 kh1 = *(const bf16x8*)&KH[base + c1];
            const bf16x8 kl0 = *(const bf16x8*)&KL[base + c0];
            const bf16x8 kl1 = *(const bf16x8*)&KL[base + c1];
            s[nt] = (f32x4){0.f, 0.f, 0.f, 0.f};
            s[nt] = __builtin_amdgcn_mfma_f32_16x16x32_bf16(qh[0], kh0, s[nt], 0, 0, 0);
            s[nt] = __builtin_amdgcn_mfma_f32_16x16x32_bf16(qh[1], kh1, s[nt], 0, 0, 0);
            s[nt] = __builtin_amdgcn_mfma_f32_16x16x32_bf16(ql[0], kh0, s[nt], 0, 0, 0);
            s[nt] = __builtin_amdgcn_mfma_f32_16x16x32_bf16(ql[1], kh1, s[nt], 0, 0, 0);
            s[nt] = __builtin_amdgcn_mfma_f32_16x16x32_bf16(qh[0], kl0, s[nt], 0, 0, 0);
            s[nt] = __builtin_amdgcn_mfma_f32_16x16x32_bf16(qh[1], kl1, s[nt], 0, 0, 0);
        }

#pragma unroll
        for (int nt = 0; nt < 4; ++nt) {
            const bool ok = mk[nt] > 0.5f;
#pragma unroll
            for (int r = 0; r < 4; ++r) s[nt][r] = ok ? s[nt][r] : -1e30f;
        }

        float alpha[4], mnew[4];
#pragma unroll
        for (int r = 0; r < 4; ++r) {
            float mt = fmaxf(fmaxf(s[0][r], s[1][r]), fmaxf(s[2][r], s[3][r]));
            mt = fmaxf(mt, __shfl_xor(mt, 1));
            mt = fmaxf(mt, __shfl_xor(mt, 2));
            mt = fmaxf(mt, __shfl_xor(mt, 4));
            mt = fmaxf(mt, __shfl_xor(mt, 8));
            mnew[r]  = fmaxf(mrow[r], mt);
            alpha[r] = __expf(mrow[r] - mnew[r]);
            mrow[r]  = mnew[r];
        }
        float p[4][4];
#pragma unroll
        for (int r = 0; r < 4; ++r) {
            float lt = 0.f;
#pragma unroll
            for (int nt = 0; nt < 4; ++nt) { p[nt][r] = __expf(s[nt][r] - mnew[r]); lt += p[nt][r]; }
            lt += __shfl_xor(lt, 1);
            lt += __shfl_xor(lt, 2);
            lt += __shfl_xor(lt, 4);
            lt += __shfl_xor(lt, 8);
            lrow[r] = lrow[r]*alpha[r] + lt;
#pragma unroll
            for (int nt = 0; nt < 4; ++nt) o[nt][r] *= alpha[r];
        }

#pragma unroll
        for (int nt = 0; nt < 4; ++nt)
#pragma unroll
            for (int r = 0; r < 4; ++r)
                Pb[w][quad*4 + r][nt*16 + lx] = p[nt][r];

        bf16x8 ph[2], pl[2];
#pragma unroll
        for (int ks = 0; ks < 2; ++ks) {
            float pv[8];
            *(f32x4*)&pv[0] = *(const f32x4*)&Pb[w][lx][ks*32 + quad*8];
            *(f32x4*)&pv[4] = *(const f32x4*)&Pb[w][lx][ks*32 + quad*8 + 4];
#pragma unroll
            for (int j = 0; j < 8; ++j) {
                const unsigned ub = fbits(pv[j]);
                ph[ks][j] = (short)(ub >> 16);
                const float lof = pv[j] - bitsf(ub & 0xffff0000u);
                pl[ks][j] = (short)(fbits(lof) >> 16);
            }
        }

#pragma unroll
        for (int nt = 0; nt < 4; ++nt) {
            const int row = nt*16 + lx;
            const int base = row*64;
            const int sw = lx & 7;
            const int c0 = ((0*4 + quad) ^ sw) * 8;
            const int c1 = ((1*4 + quad) ^ sw) * 8;
            const bf16x8 vh0 = *(const bf16x8*)&VH[base + c0];
            const bf16x8 vh1 = *(const bf16x8*)&VH[base + c1];
            const bf16x8 vl0 = *(const bf16x8*)&VL[base + c0];
            const bf16x8 vl1 = *(const bf16x8*)&VL[base + c1];
            o[nt] = __builtin_amdgcn_mfma_f32_16x16x32_bf16(ph[0], vh0, o[nt], 0, 0, 0);
            o[nt] = __builtin_amdgcn_mfma_f32_16x16x32_bf16(ph[1], vh1, o[nt], 0, 0, 0);
            o[nt] = __builtin_amdgcn_mfma_f32_16x16x32_bf16(pl[0], vh0, o[nt], 0, 0, 0);
            o[nt] = __builtin_amdgcn_mfma_f32_16x16x32_bf16(pl[1], vh1, o[nt], 0, 0, 0);
            o[nt] = __builtin_amdgcn_mfma_f32_16x16x32_bf16(ph[0], vl0, o[nt], 0, 0, 0);
            o[nt] = __builtin_amdgcn_mfma_f32_16x16x32_bf16(ph[1], vl1, o[nt], 0, 0, 0);
        }

        __syncthreads();
#pragma unroll
        for (int p2 = 0; p2 < 2; ++p2) {
            *(bf16x8*)&KH[lw[p2]] = rkh[p2];
            *(bf16x8*)&KL[lw[p2]] = rkl[p2];
            *(bf16x8*)&VH[lw[p2]] = rvh[p2];
            *(bf16x8*)&VL[lw[p2]] = rvl[p2];
        }
        __syncthreads();
    }

    float inv[4];
#pragma unroll
    for (int r = 0; r < 4; ++r) inv[r] = 1.0f / lrow[r];
#pragma unroll
    for (int nt = 0; nt < 4; ++nt)
#pragma unroll
        for (int r = 0; r < 4; ++r) {
            const int t = qrow0 + quad*4 + r;
            O[(((size_t)b)*T_SEQ + t)*DM + h*HD + nt*16 + lx] = o[nt][r] * inv[r];
        }
}

// -------------------------------------------------------------------------
// Memory plan (unchanged from R7).
// -------------------------------------------------------------------------
extern "C" void kernel_launch(void* const* d_in, const int* in_sizes, int n_in,
                              void* d_out, int out_size, void* d_ws, size_t ws_size,
                              hipStream_t stream)
{
    const float* tokens = (const float*)d_in[0];
    const int*   pad    = (const int*)d_in[1];
    const float* Wqkv   = (const float*)d_in[2];
    const float* bqkv   = (const float*)d_in[3];
    const float* Wout   = (const float*)d_in[4];
    const float* bout   = (const float*)d_in[5];
    float* out = (float*)d_out;

    const size_t SZ = (size_t)8388608;
    ushort_t* U = (ushort_t*)d_ws;
    ushort_t* Qhi  = U;
    ushort_t* Qlo  = U + SZ;
    ushort_t* Khi  = U + 2*SZ;
    ushort_t* Klo  = U + 3*SZ;
    ushort_t* Vthi = U + 4*SZ;
    ushort_t* Vtlo = U + 5*SZ;
    float* MSK = (float*)(U + 6*SZ);
    float* AO  = MSK + 8192;
    ushort_t* WqkvTh = (ushort_t*)AO;
    ushort_t* WqkvTl = WqkvTh + (size_t)3*DM*DM;
    ushort_t* TokH = (ushort_t*)d_out;             // scratch in d_out
    ushort_t* TokL = TokH + SZ;
    ushort_t* AOh  = Qhi;                          // reuse after attention
    ushort_t* AOl  = Qlo;
    ushort_t* WoutTh = Khi;
    ushort_t* WoutTl = Khi + (size_t)DM*DM;

    maskprep_kernel<<<dim3(BATCH), dim3(256), 0, stream>>>(pad, MSK);
    split_kernel<<<dim3(8192), dim3(256), 0, stream>>>(tokens, TokH, TokL);
    transpose_split_kernel<<<dim3(48, 16), dim3(256), 0, stream>>>(
        Wqkv, WqkvTh, WqkvTl, DM, 3*DM);
    mfma_gemm_kernel<1><<<dim3(24, 64), dim3(256), 0, stream>>>(
        TokH, TokL, WqkvTh, WqkvTl, bqkv, nullptr,
        Qhi, Qlo, Khi, Klo, Vthi, Vtlo, BATCH*T_SEQ, 3*DM, DM);
    attn_mfma_kernel<<<dim3(2048), dim3(256), 0, stream>>>(
        Qhi, Qlo, Khi, Klo, Vthi, Vtlo, MSK, AO);
    split_kernel<<<dim3(8192), dim3(256), 0, stream>>>(AO, AOh, AOl);
    transpose_split_kernel<<<dim3(16, 16), dim3(256), 0, stream>>>(
        Wout, WoutTh, WoutTl, DM, DM);
    mfma_gemm_kernel<0><<<dim3(8, 64), dim3(256), 0, stream>>>(
        AOh, AOl, WoutTh, WoutTl, bout, out,
        nullptr, nullptr, nullptr, nullptr, nullptr, nullptr, BATCH*T_SEQ, DM, DM);
}

// Round 9
// 685.215 us; speedup vs baseline: 2.0093x; 2.0093x over previous
//
#include <hip/hip_runtime.h>
#include <cmath>

#define T_SEQ 2048
#define NH    16
#define HD    64
#define DM    1024
#define BATCH 4

typedef __attribute__((ext_vector_type(8))) short bf16x8;
typedef __attribute__((ext_vector_type(4))) float f32x4;
typedef unsigned short ushort_t;

__device__ __forceinline__ unsigned short f2bf(float x) {   // rne fp32->bf16
    union { float f; unsigned u; } v; v.f = x;
    unsigned r = v.u + 0x7fffu + ((v.u >> 16) & 1u);
    return (unsigned short)(r >> 16);
}
__device__ __forceinline__ float bf2f(unsigned short h) {
    union { unsigned u; float f; } v; v.u = ((unsigned)h) << 16;
    return v.f;
}
__device__ __forceinline__ unsigned fbits(float x) {
    union { float f; unsigned u; } v; v.f = x; return v.u;
}
__device__ __forceinline__ float bitsf(unsigned x) {
    union { unsigned u; float f; } v; v.u = x; return v.f;
}

// async global->LDS DMA, 16 B per lane (verified R7: correct staging).
__device__ __forceinline__ void dma16(const void* g, const void* l) {
    __builtin_amdgcn_global_load_lds(
        (const __attribute__((address_space(1))) unsigned int*)(unsigned long long)g,
        (__attribute__((address_space(3))) unsigned int*)(unsigned int)(unsigned long long)l,
        16, 0, 0);
}

// -------------------------------------------------------------------------
// Kernel 1: mask prep (unchanged).
// -------------------------------------------------------------------------
__global__ void maskprep_kernel(const int* __restrict__ pad, float* __restrict__ valid)
{
    __shared__ int sall[256];
    const int b = blockIdx.x;
    const int t = threadIdx.x;
    int allp = 1;
    for (int i = t; i < T_SEQ; i += 256) allp &= (pad[b*T_SEQ + i] != 0) ? 1 : 0;
    sall[t] = allp;
    __syncthreads();
    for (int s = 128; s > 0; s >>= 1) {
        if (t < s) sall[t] &= sall[t + s];
        __syncthreads();
    }
    const int ap = sall[0];
    for (int i = t; i < T_SEQ; i += 256) {
        const int p = (pad[b*T_SEQ + i] != 0) ? 1 : 0;
        valid[b*T_SEQ + i] = (p && !ap) ? 0.0f : 1.0f;
    }
}

// -------------------------------------------------------------------------
// Kernel 2: weight transpose+split (unchanged). W[K][N] -> Th/Tl[N][K].
// -------------------------------------------------------------------------
__global__ __launch_bounds__(256)
void transpose_split_kernel(const float* __restrict__ W,
                            ushort_t* __restrict__ Th, ushort_t* __restrict__ Tl,
                            int K, int N)
{
    __shared__ float T[64][68];
    const int tid = threadIdx.x;
    const int n0 = blockIdx.x * 64;
    const int k0 = blockIdx.y * 64;
#pragma unroll
    for (int i = 0; i < 4; ++i) {
        const int kr = (tid >> 4) + i*16;
        const int nc = (tid & 15) * 4;
        const float4 v = *(const float4*)&W[(size_t)(k0 + kr)*N + n0 + nc];
        T[nc+0][kr] = v.x; T[nc+1][kr] = v.y; T[nc+2][kr] = v.z; T[nc+3][kr] = v.w;
    }
    __syncthreads();
#pragma unroll
    for (int i = 0; i < 4; ++i) {
        const int nr = (tid >> 4) + i*16;
        const int kc = (tid & 15) * 4;
        ushort_t h[4], l[4];
#pragma unroll
        for (int j = 0; j < 4; ++j) {
            const float x = T[nr][kc + j];
            h[j] = f2bf(x);
            l[j] = f2bf(x - bf2f(h[j]));
        }
        const size_t off = (size_t)(n0 + nr)*K + k0 + kc;
        *(short4*)&Th[off] = make_short4(h[0], h[1], h[2], h[3]);
        *(short4*)&Tl[off] = make_short4(l[0], l[1], l[2], l[3]);
    }
}

// -------------------------------------------------------------------------
// Kernel 2b: row-major fp32 -> bf16 hi/lo split (unchanged).
// -------------------------------------------------------------------------
__global__ __launch_bounds__(256)
void split_kernel(const float* __restrict__ X,
                  ushort_t* __restrict__ H, ushort_t* __restrict__ L)
{
    const int i = blockIdx.x * 256 + threadIdx.x;     // float4 index
    const float4 v = ((const float4*)X)[i];
    const float x[4] = {v.x, v.y, v.z, v.w};
    ushort_t h[4], l[4];
#pragma unroll
    for (int j = 0; j < 4; ++j) {
        const unsigned u = fbits(x[j]);
        h[j] = (ushort_t)(u >> 16);
        l[j] = f2bf(x[j] - bitsf(u & 0xffff0000u));
    }
    *(short4*)&H[(size_t)i*4] = make_short4(h[0], h[1], h[2], h[3]);
    *(short4*)&L[(size_t)i*4] = make_short4(l[0], l[1], l[2], l[3]);
}

// -------------------------------------------------------------------------
// Kernel 3/5: split-bf16 MFMA GEMM. R9: block tile 64x128xBK32, wave tile
// 32x64 (acc = 32 AGPRs, arch-VGPR demand ~70 — below the allocator's
// ~90-reg allotment at its chosen occupancy, so the scratch-spill leak
// (R5-R8: 3.2-5.5 GB WRITE_SIZE = spilled frag/acc round-trips) has
// nothing left to spill). A-frags read per-mt to cap live frags at ~10.
// LDS: Ah/Al 4 KB + Bh/Bl 8 KB = 24 KB; epilogue union 34 KB.
// -------------------------------------------------------------------------
template<int EPI>
__global__ __launch_bounds__(256)
void mfma_gemm_kernel(const ushort_t* __restrict__ Ath, const ushort_t* __restrict__ Atl,
                      const ushort_t* __restrict__ BTh, const ushort_t* __restrict__ BTl,
                      const float* __restrict__ bias,
                      float* __restrict__ O0,
                      ushort_t* __restrict__ Qhi, ushort_t* __restrict__ Qlo,
                      ushort_t* __restrict__ Khi, ushort_t* __restrict__ Klo,
                      ushort_t* __restrict__ Vthi, ushort_t* __restrict__ Vtlo,
                      int M, int N, int K)
{
    __shared__ __align__(16) char smem[34816];
    char* smAh = smem;             // [64][32] bf16 = 4 KB
    char* smAl = smem + 4096;
    char* smBh = smem + 8192;      // [128][32] bf16 = 8 KB
    char* smBl = smem + 16384;

    const int tid  = threadIdx.x;
    const int w    = tid >> 6;
    const int ln   = tid & 63;
    const int lx   = ln & 15;
    const int quad = ln >> 4;
    const int mw   = (w >> 1) * 32;       // wave m-offset (0|32)
    const int nw   = (w & 1) * 64;        // wave n-offset (0|64)
    const int m0   = blockIdx.y * 64;
    const int n0   = blockIdx.x * 128;

    // DMA geometry. A (4 KB): wave w stages rows [w*16, w*16+16), lane ln ->
    // row w*16 + ln/4, chunk ln&3; 1 instr/array/wave.
    // B (8 KB): rows w*32 + j*16 + ln/4, j=0..1; 2 instr/array/wave.
    const size_t gaA = (size_t)(m0 + w*16 + (ln >> 2))*K + (ln & 3)*8;
    const size_t gaB = (size_t)(n0 + w*32 + (ln >> 2))*K + (ln & 3)*8;
    const int ldsA = (w*64 + ln)*16;
    const int ldsB = (w*128 + ln)*16;

#define ISSUE_DMA(kk) do {                                               \
        dma16(Ath + gaA + (kk),        smAh + ldsA);                     \
        dma16(Atl + gaA + (kk),        smAl + ldsA);                     \
        dma16(BTh + gaB + (kk),        smBh + ldsB);                     \
        dma16(BTh + gaB + 16*K + (kk), smBh + ldsB + 1024);              \
        dma16(BTl + gaB + (kk),        smBl + ldsB);                     \
        dma16(BTl + gaB + 16*K + (kk), smBl + ldsB + 1024);              \
    } while (0)

    f32x4 acc[2][4];
#pragma unroll
    for (int mt = 0; mt < 2; ++mt)
#pragma unroll
        for (int nt = 0; nt < 4; ++nt) acc[mt][nt] = (f32x4){0.f,0.f,0.f,0.f};

    ISSUE_DMA(0);

    for (int kk = 0; kk < K; kk += 32) {
        __syncthreads();                       // DMA for tile kk landed

        bf16x8 bfh[4], bfl[4];
#pragma unroll
        for (int nt = 0; nt < 4; ++nt) {
            const int off = (nw + nt*16 + lx)*64 + quad*16;
            bfh[nt] = *(const bf16x8*)(smBh + off);
            bfl[nt] = *(const bf16x8*)(smBl + off);
        }
        bf16x8 afh0, afl0, afh1, afl1;
        {
            const int o0 = (mw + lx)*64 + quad*16;
            const int o1 = (mw + 16 + lx)*64 + quad*16;
            afh0 = *(const bf16x8*)(smAh + o0);
            afl0 = *(const bf16x8*)(smAl + o0);
            afh1 = *(const bf16x8*)(smAh + o1);
            afl1 = *(const bf16x8*)(smAl + o1);
        }
        __syncthreads();                       // all reads done; tile reusable
        if (kk + 32 < K) ISSUE_DMA(kk + 32);   // async while we MFMA

#pragma unroll
        for (int nt = 0; nt < 4; ++nt) {
            acc[0][nt] = __builtin_amdgcn_mfma_f32_16x16x32_bf16(afh0, bfh[nt], acc[0][nt], 0, 0, 0);
            acc[0][nt] = __builtin_amdgcn_mfma_f32_16x16x32_bf16(afh0, bfl[nt], acc[0][nt], 0, 0, 0);
            acc[0][nt] = __builtin_amdgcn_mfma_f32_16x16x32_bf16(afl0, bfh[nt], acc[0][nt], 0, 0, 0);
        }
#pragma unroll
        for (int nt = 0; nt < 4; ++nt) {
            acc[1][nt] = __builtin_amdgcn_mfma_f32_16x16x32_bf16(afh1, bfh[nt], acc[1][nt], 0, 0, 0);
            acc[1][nt] = __builtin_amdgcn_mfma_f32_16x16x32_bf16(afh1, bfl[nt], acc[1][nt], 0, 0, 0);
            acc[1][nt] = __builtin_amdgcn_mfma_f32_16x16x32_bf16(afl1, bfh[nt], acc[1][nt], 0, 0, 0);
        }
    }
#undef ISSUE_DMA

    // ---------------- epilogue ----------------
    if (EPI == 0) {
#pragma unroll
        for (int nt = 0; nt < 4; ++nt) {
            const int n = n0 + nw + nt*16 + lx;
#pragma unroll
            for (int mt = 0; mt < 2; ++mt)
#pragma unroll
                for (int r = 0; r < 4; ++r) {
                    const int m = m0 + mw + mt*16 + quad*4 + r;
                    O0[(size_t)m*N + n] = acc[mt][nt][r] + bias[n];
                }
        }
    } else {
        const int which = n0 >> 10;           // block-uniform: 0=q 1=k 2=v
        const int hbase = (n0 & 1023) >> 6;
        const int b     = m0 >> 11;
        const int t0    = m0 & 2047;
        float* Ct = (float*)smem;             // Q/K: [64][132]; V: [128][68]
        const float ssign = (lx & 1) ? 1.0f : -1.0f;

        __syncthreads();                      // k-loop LDS reads all done
        if (which < 2) {
#pragma unroll
            for (int nt = 0; nt < 4; ++nt) {
                const int nl = nw + nt*16 + lx;
                const int d  = nl & 63;
                const float bn = bias[n0 + nl];
                const float freq = expf(-(float)(d >> 1) * 0.28782313662425575f);
#pragma unroll
                for (int mt = 0; mt < 2; ++mt)
#pragma unroll
                    for (int r = 0; r < 4; ++r) {
                        const int ml = mw + mt*16 + quad*4 + r;
                        const int t  = t0 + ml;
                        float res = acc[mt][nt][r] + bn;
                        const float ang = (float)t * freq;
                        const float sn = sinf(ang), cs = cosf(ang);
                        const float prt = __shfl_xor(res, 1);
                        res = res*cs + ssign*prt*sn;
                        if (which == 0) res *= 0.125f;
                        Ct[ml*132 + nl] = res;
                    }
            }
        } else {
#pragma unroll
            for (int nt = 0; nt < 4; ++nt) {
                const int nl = nw + nt*16 + lx;
                const float bn = bias[n0 + nl];
#pragma unroll
                for (int mt = 0; mt < 2; ++mt)
#pragma unroll
                    for (int r = 0; r < 4; ++r) {
                        const int ml = mw + mt*16 + quad*4 + r;
                        Ct[nl*68 + ml] = acc[mt][nt][r] + bn;
                    }
            }
        }
        __syncthreads();

        if (which < 2) {
            ushort_t* dH = which ? Khi : Qhi;
            ushort_t* dL = which ? Klo : Qlo;
#pragma unroll
            for (int u = 0; u < 4; ++u) {
                const int L  = u*32 + (tid >> 3);    // 0..127
                const int t  = L & 63;
                const int hl = L >> 6;
                const int dg = (tid & 7) * 8;
                const float* src = &Ct[t*132 + hl*64 + dg];
                float v[8];
                *(f32x4*)&v[0] = *(const f32x4*)src;
                *(f32x4*)&v[4] = *(const f32x4*)(src + 4);
                bf16x8 h8, l8;
#pragma unroll
                for (int j = 0; j < 8; ++j) {
                    const unsigned u32 = fbits(v[j]);
                    h8[j] = (short)(u32 >> 16);
                    l8[j] = (short)f2bf(v[j] - bitsf(u32 & 0xffff0000u));
                }
                const int bh = b*NH + hbase + hl;
                const size_t off = (((size_t)bh)*T_SEQ + t0 + t)*64 + dg;
                *(bf16x8*)&dH[off] = h8;
                *(bf16x8*)&dL[off] = l8;
            }
        } else {
#pragma unroll
            for (int u = 0; u < 4; ++u) {
                const int row = u*32 + (tid >> 3);   // 0..127
                const int d   = row & 63;
                const int hl  = row >> 6;
                const int tg  = (tid & 7) * 8;
                const float* src = &Ct[row*68 + tg];
                float v[8];
                *(f32x4*)&v[0] = *(const f32x4*)src;
                *(f32x4*)&v[4] = *(const f32x4*)(src + 4);
                bf16x8 h8, l8;
#pragma unroll
                for (int j = 0; j < 8; ++j) {
                    const unsigned u32 = fbits(v[j]);
                    h8[j] = (short)(u32 >> 16);
                    l8[j] = (short)f2bf(v[j] - bitsf(u32 & 0xffff0000u));
                }
                const int bh = b*NH + hbase + hl;
                const size_t off = (((size_t)bh)*HD + d)*T_SEQ + t0 + tg;
                *(bf16x8*)&Vthi[off] = h8;
                *(bf16x8*)&Vtlo[off] = l8;
            }
        }
    }
}

// -------------------------------------------------------------------------
// Kernel 4: flash attention (unchanged — verified).
// -------------------------------------------------------------------------
__global__ __launch_bounds__(256, 2)
void attn_mfma_kernel(const ushort_t* __restrict__ Qhi, const ushort_t* __restrict__ Qlo,
                      const ushort_t* __restrict__ Khi, const ushort_t* __restrict__ Klo,
                      const ushort_t* __restrict__ Vthi, const ushort_t* __restrict__ Vtlo,
                      const float* __restrict__ valid, float* __restrict__ O)
{
    __shared__ ushort_t KH[64*64];
    __shared__ ushort_t KL[64*64];
    __shared__ ushort_t VH[64*64];
    __shared__ ushort_t VL[64*64];
    __shared__ float Pb[4][16][68];

    const int tid  = threadIdx.x;
    const int w    = tid >> 6;
    const int ln   = tid & 63;
    const int lx   = ln & 15;
    const int quad = ln >> 4;

    const int id = blockIdx.x;
    const int qt = (id >> 3) & 31;
    const int bh = ((id >> 8) << 3) | (id & 7);
    const int b  = bh >> 4;
    const int h  = bh & 15;
    const int qrow0 = qt*64 + w*16;

    bf16x8 qh[2], ql[2];
    {
        const size_t qoff = (((size_t)bh)*T_SEQ + qrow0 + lx)*HD + quad*8;
        qh[0] = *(const bf16x8*)&Qhi[qoff];
        qh[1] = *(const bf16x8*)&Qhi[qoff + 32];
        ql[0] = *(const bf16x8*)&Qlo[qoff];
        ql[1] = *(const bf16x8*)&Qlo[qoff + 32];
    }

    const int srow0 = w*16 + (ln >> 3);
    const int sch   = ln & 7;
    const size_t kg0 = ((size_t)bh*T_SEQ + srow0)*HD + sch*8;
    const size_t vg0 = ((size_t)bh*HD + srow0)*T_SEQ + sch*8;
    int lw[2];
#pragma unroll
    for (int p = 0; p < 2; ++p) {
        const int r = srow0 + p*8;
        lw[p] = r*64 + ((sch ^ (r & 7)) * 8);
    }

    const float* vrow = valid + (size_t)b*T_SEQ + lx;

    f32x4 o[4];
#pragma unroll
    for (int nt = 0; nt < 4; ++nt) o[nt] = (f32x4){0.f, 0.f, 0.f, 0.f};
    float mrow[4] = {-INFINITY, -INFINITY, -INFINITY, -INFINITY};
    float lrow[4] = {0.f, 0.f, 0.f, 0.f};

    bf16x8 rkh[2], rkl[2], rvh[2], rvl[2];
#pragma unroll
    for (int p = 0; p < 2; ++p) {
        rkh[p] = *(const bf16x8*)&Khi [kg0 + p*8*HD];
        rkl[p] = *(const bf16x8*)&Klo [kg0 + p*8*HD];
        rvh[p] = *(const bf16x8*)&Vthi[vg0 + p*8*T_SEQ];
        rvl[p] = *(const bf16x8*)&Vtlo[vg0 + p*8*T_SEQ];
    }
#pragma unroll
    for (int p = 0; p < 2; ++p) {
        *(bf16x8*)&KH[lw[p]] = rkh[p];
        *(bf16x8*)&KL[lw[p]] = rkl[p];
        *(bf16x8*)&VH[lw[p]] = rvh[p];
        *(bf16x8*)&VL[lw[p]] = rvl[p];
    }
    __syncthreads();

    for (int kt = 0; kt < T_SEQ/64; ++kt) {
        const int ktn = (kt+1 < T_SEQ/64) ? kt+1 : kt;
#pragma unroll
        for (int p = 0; p < 2; ++p) {
            rkh[p] = *(const bf16x8*)&Khi [kg0 + (size_t)ktn*64*HD + p*8*HD];
            rkl[p] = *(const bf16x8*)&Klo [kg0 + (size_t)ktn*64*HD + p*8*HD];
            rvh[p] = *(const bf16x8*)&Vthi[vg0 + ktn*64 + p*8*T_SEQ];
            rvl[p] = *(const bf16x8*)&Vtlo[vg0 + ktn*64 + p*8*T_SEQ];
        }
        float mk[4];
#pragma unroll
        for (int nt = 0; nt < 4; ++nt) mk[nt] = vrow[kt*64 + nt*16];

        f32x4 s[4];
#pragma unroll
        for (int nt = 0; nt < 4; ++nt) {
            const int row = nt*16 + lx;
            const int base = row*64;
            const int sw = lx & 7;
            const int c0 = ((0*4 + quad) ^ sw) * 8;
            const int c1 = ((1*4 + quad) ^ sw) * 8;
            const bf16x8 kh0 = *(const bf16x8*)&KH[base + c0];
            const bf16x8 kh1 = *(const bf16x8*)&KH[base + c1];
            const bf16x8 kl0 = *(const bf16x8*)&KL[base + c0];
            const bf16x8 kl1 = *(const bf16x8*)&KL[base + c1];
            s[nt] = (f32x4){0.f, 0.f, 0.f, 0.f};
            s[nt] = __builtin_amdgcn_mfma_f32_16x16x32_bf16(qh[0], kh0, s[nt], 0, 0, 0);
            s[nt] = __builtin_amdgcn_mfma_f32_16x16x32_bf16(qh[1], kh1, s[nt], 0, 0, 0);
            s[nt] = __builtin_amdgcn_mfma_f32_16x16x32_bf16(ql[0], kh0, s[nt], 0, 0, 0);
            s[nt] = __builtin_amdgcn_mfma_f32_16x16x32_bf16(ql[1], kh1, s[nt], 0, 0, 0);
            s[nt] = __builtin_amdgcn_mfma_f32_16x16x32_bf16(qh[0], kl0, s[nt], 0, 0, 0);
            s[nt] = __builtin_amdgcn_mfma_f32_16x16x32_bf16(qh[1], kl1, s[nt], 0, 0, 0);
        }

#pragma unroll
        for (int nt = 0; nt < 4; ++nt) {
            const bool ok = mk[nt] > 0.5f;
#pragma unroll
            for (int r = 0; r < 4; ++r) s[nt][r] = ok ? s[nt][r] : -1e30f;
        }

        float alpha[4], mnew[4];
#pragma unroll
        for (int r = 0; r < 4; ++r) {
            float mt = fmaxf(fmaxf(s[0][r], s[1][r]), fmaxf(s[2][r], s[3][r]));
            mt = fmaxf(mt, __shfl_xor(mt, 1));
            mt = fmaxf(mt, __shfl_xor(mt, 2));
            mt = fmaxf(mt, __shfl_xor(mt, 4));
            mt = fmaxf(mt, __shfl_xor(mt, 8));
            mnew[r]  = fmaxf(mrow[r], mt);
            alpha[r] = __expf(mrow[r] - mnew[r]);
            mrow[r]  = mnew[r];
        }
        float p[4][4];
#pragma unroll
        for (int r = 0; r < 4; ++r) {
            float lt = 0.f;
#pragma unroll
            for (int nt = 0; nt < 4; ++nt) { p[nt][r] = __expf(s[nt][r] - mnew[r]); lt += p[nt][r]; }
            lt += __shfl_xor(lt, 1);
            lt += __shfl_xor(lt, 2);
            lt += __shfl_xor(lt, 4);
            lt += __shfl_xor(lt, 8);
            lrow[r] = lrow[r]*alpha[r] + lt;
#pragma unroll
            for (int nt = 0; nt < 4; ++nt) o[nt][r] *= alpha[r];
        }

#pragma unroll
        for (int nt = 0; nt < 4; ++nt)
#pragma unroll
            for (int r = 0; r < 4; ++r)
                Pb[w][quad*4 + r][nt*16 + lx] = p[nt][r];

        bf16x8 ph[2], pl[2];
#pragma unroll
        for (int ks = 0; ks < 2; ++ks) {
            float pv[8];
            *(f32x4*)&pv[0] = *(const f32x4*)&Pb[w][lx][ks*32 + quad*8];
            *(f32x4*)&pv[4] = *(const f32x4*)&Pb[w][lx][ks*32 + quad*8 + 4];
#pragma unroll
            for (int j = 0; j < 8; ++j) {
                const unsigned ub = fbits(pv[j]);
                ph[ks][j] = (short)(ub >> 16);
                const float lof = pv[j] - bitsf(ub & 0xffff0000u);
                pl[ks][j] = (short)(fbits(lof) >> 16);
            }
        }

#pragma unroll
        for (int nt = 0; nt < 4; ++nt) {
            const int row = nt*16 + lx;
            const int base = row*64;
            const int sw = lx & 7;
            const int c0 = ((0*4 + quad) ^ sw) * 8;
            const int c1 = ((1*4 + quad) ^ sw) * 8;
            const bf16x8 vh0 = *(const bf16x8*)&VH[base + c0];
            const bf16x8 vh1 = *(const bf16x8*)&VH[base + c1];
            const bf16x8 vl0 = *(const bf16x8*)&VL[base + c0];
            const bf16x8 vl1 = *(const bf16x8*)&VL[base + c1];
            o[nt] = __builtin_amdgcn_mfma_f32_16x16x32_bf16(ph[0], vh0, o[nt], 0, 0, 0);
            o[nt] = __builtin_amdgcn_mfma_f32_16x16x32_bf16(ph[1], vh1, o[nt], 0, 0, 0);
            o[nt] = __builtin_amdgcn_mfma_f32_16x16x32_bf16(pl[0], vh0, o[nt], 0, 0, 0);
            o[nt] = __builtin_amdgcn_mfma_f32_16x16x32_bf16(pl[1], vh1, o[nt], 0, 0, 0);
            o[nt] = __builtin_amdgcn_mfma_f32_16x16x32_bf16(ph[0], vl0, o[nt], 0, 0, 0);
            o[nt] = __builtin_amdgcn_mfma_f32_16x16x32_bf16(ph[1], vl1, o[nt], 0, 0, 0);
        }

        __syncthreads();
#pragma unroll
        for (int p2 = 0; p2 < 2; ++p2) {
            *(bf16x8*)&KH[lw[p2]] = rkh[p2];
            *(bf16x8*)&KL[lw[p2]] = rkl[p2];
            *(bf16x8*)&VH[lw[p2]] = rvh[p2];
            *(bf16x8*)&VL[lw[p2]] = rvl[p2];
        }
        __syncthreads();
    }

    float inv[4];
#pragma unroll
    for (int r = 0; r < 4; ++r) inv[r] = 1.0f / lrow[r];
#pragma unroll
    for (int nt = 0; nt < 4; ++nt)
#pragma unroll
        for (int r = 0; r < 4; ++r) {
            const int t = qrow0 + quad*4 + r;
            O[(((size_t)b)*T_SEQ + t)*DM + h*HD + nt*16 + lx] = o[nt][r] * inv[r];
        }
}

// -------------------------------------------------------------------------
// Memory plan (unchanged from R7/R8).
// -------------------------------------------------------------------------
extern "C" void kernel_launch(void* const* d_in, const int* in_sizes, int n_in,
                              void* d_out, int out_size, void* d_ws, size_t ws_size,
                              hipStream_t stream)
{
    const float* tokens = (const float*)d_in[0];
    const int*   pad    = (const int*)d_in[1];
    const float* Wqkv   = (const float*)d_in[2];
    const float* bqkv   = (const float*)d_in[3];
    const float* Wout   = (const float*)d_in[4];
    const float* bout   = (const float*)d_in[5];
    float* out = (float*)d_out;

    const size_t SZ = (size_t)8388608;
    ushort_t* U = (ushort_t*)d_ws;
    ushort_t* Qhi  = U;
    ushort_t* Qlo  = U + SZ;
    ushort_t* Khi  = U + 2*SZ;
    ushort_t* Klo  = U + 3*SZ;
    ushort_t* Vthi = U + 4*SZ;
    ushort_t* Vtlo = U + 5*SZ;
    float* MSK = (float*)(U + 6*SZ);
    float* AO  = MSK + 8192;
    ushort_t* WqkvTh = (ushort_t*)AO;
    ushort_t* WqkvTl = WqkvTh + (size_t)3*DM*DM;
    ushort_t* TokH = (ushort_t*)d_out;             // scratch in d_out
    ushort_t* TokL = TokH + SZ;
    ushort_t* AOh  = Qhi;                          // reuse after attention
    ushort_t* AOl  = Qlo;
    ushort_t* WoutTh = Khi;
    ushort_t* WoutTl = Khi + (size_t)DM*DM;

    maskprep_kernel<<<dim3(BATCH), dim3(256), 0, stream>>>(pad, MSK);
    split_kernel<<<dim3(8192), dim3(256), 0, stream>>>(tokens, TokH, TokL);
    transpose_split_kernel<<<dim3(48, 16), dim3(256), 0, stream>>>(
        Wqkv, WqkvTh, WqkvTl, DM, 3*DM);
    mfma_gemm_kernel<1><<<dim3(24, 128), dim3(256), 0, stream>>>(
        TokH, TokL, WqkvTh, WqkvTl, bqkv, nullptr,
        Qhi, Qlo, Khi, Klo, Vthi, Vtlo, BATCH*T_SEQ, 3*DM, DM);
    attn_mfma_kernel<<<dim3(2048), dim3(256), 0, stream>>>(
        Qhi, Qlo, Khi, Klo, Vthi, Vtlo, MSK, AO);
    split_kernel<<<dim3(8192), dim3(256), 0, stream>>>(AO, AOh, AOl);
    transpose_split_kernel<<<dim3(16, 16), dim3(256), 0, stream>>>(
        Wout, WoutTh, WoutTl, DM, DM);
    mfma_gemm_kernel<0><<<dim3(8, 128), dim3(256), 0, stream>>>(
        AOh, AOl, WoutTh, WoutTl, bout, out,
        nullptr, nullptr, nullptr, nullptr, nullptr, nullptr, BATCH*T_SEQ, DM, DM);
}

// Round 11
// 677.463 us; speedup vs baseline: 2.0323x; 1.0114x over previous
//
#include <hip/hip_runtime.h>
#include <cmath>

#define T_SEQ 2048
#define NH    16
#define HD    64
#define DM    1024
#define BATCH 4

typedef __attribute__((ext_vector_type(8))) short bf16x8;
typedef __attribute__((ext_vector_type(4))) float f32x4;
typedef unsigned short ushort_t;

__device__ __forceinline__ unsigned short f2bf(float x) {   // rne fp32->bf16
    union { float f; unsigned u; } v; v.f = x;
    unsigned r = v.u + 0x7fffu + ((v.u >> 16) & 1u);
    return (unsigned short)(r >> 16);
}
__device__ __forceinline__ float bf2f(unsigned short h) {
    union { unsigned u; float f; } v; v.u = ((unsigned)h) << 16;
    return v.f;
}
__device__ __forceinline__ unsigned fbits(float x) {
    union { float f; unsigned u; } v; v.f = x; return v.u;
}
__device__ __forceinline__ float bitsf(unsigned x) {
    union { unsigned u; float f; } v; v.u = x; return v.f;
}
// raw v_exp_f32 (2^x) — __exp2f doesn't exist on this ROCm (R10 compile fail)
__device__ __forceinline__ float exp2_raw(float x) {
    return __builtin_amdgcn_exp2f(x);
}

// async global->LDS DMA, 16 B per lane (verified R7/R9).
__device__ __forceinline__ void dma16(const void* g, const void* l) {
    __builtin_amdgcn_global_load_lds(
        (const __attribute__((address_space(1))) unsigned int*)(unsigned long long)g,
        (__attribute__((address_space(3))) unsigned int*)(unsigned int)(unsigned long long)l,
        16, 0, 0);
}

// -------------------------------------------------------------------------
// Kernel 1: mask prep (unchanged).
// -------------------------------------------------------------------------
__global__ void maskprep_kernel(const int* __restrict__ pad, float* __restrict__ valid)
{
    __shared__ int sall[256];
    const int b = blockIdx.x;
    const int t = threadIdx.x;
    int allp = 1;
    for (int i = t; i < T_SEQ; i += 256) allp &= (pad[b*T_SEQ + i] != 0) ? 1 : 0;
    sall[t] = allp;
    __syncthreads();
    for (int s = 128; s > 0; s >>= 1) {
        if (t < s) sall[t] &= sall[t + s];
        __syncthreads();
    }
    const int ap = sall[0];
    for (int i = t; i < T_SEQ; i += 256) {
        const int p = (pad[b*T_SEQ + i] != 0) ? 1 : 0;
        valid[b*T_SEQ + i] = (p && !ap) ? 0.0f : 1.0f;
    }
}

// -------------------------------------------------------------------------
// Kernel 2: weight transpose+split (unchanged). W[K][N] -> Th/Tl[N][K].
// -------------------------------------------------------------------------
__global__ __launch_bounds__(256)
void transpose_split_kernel(const float* __restrict__ W,
                            ushort_t* __restrict__ Th, ushort_t* __restrict__ Tl,
                            int K, int N)
{
    __shared__ float T[64][68];
    const int tid = threadIdx.x;
    const int n0 = blockIdx.x * 64;
    const int k0 = blockIdx.y * 64;
#pragma unroll
    for (int i = 0; i < 4; ++i) {
        const int kr = (tid >> 4) + i*16;
        const int nc = (tid & 15) * 4;
        const float4 v = *(const float4*)&W[(size_t)(k0 + kr)*N + n0 + nc];
        T[nc+0][kr] = v.x; T[nc+1][kr] = v.y; T[nc+2][kr] = v.z; T[nc+3][kr] = v.w;
    }
    __syncthreads();
#pragma unroll
    for (int i = 0; i < 4; ++i) {
        const int nr = (tid >> 4) + i*16;
        const int kc = (tid & 15) * 4;
        ushort_t h[4], l[4];
#pragma unroll
        for (int j = 0; j < 4; ++j) {
            const float x = T[nr][kc + j];
            h[j] = f2bf(x);
            l[j] = f2bf(x - bf2f(h[j]));
        }
        const size_t off = (size_t)(n0 + nr)*K + k0 + kc;
        *(short4*)&Th[off] = make_short4(h[0], h[1], h[2], h[3]);
        *(short4*)&Tl[off] = make_short4(l[0], l[1], l[2], l[3]);
    }
}

// -------------------------------------------------------------------------
// Kernel 2b: row-major fp32 -> bf16 hi/lo split (tokens only now).
// -------------------------------------------------------------------------
__global__ __launch_bounds__(256)
void split_kernel(const float* __restrict__ X,
                  ushort_t* __restrict__ H, ushort_t* __restrict__ L)
{
    const int i = blockIdx.x * 256 + threadIdx.x;     // float4 index
    const float4 v = ((const float4*)X)[i];
    const float x[4] = {v.x, v.y, v.z, v.w};
    ushort_t h[4], l[4];
#pragma unroll
    for (int j = 0; j < 4; ++j) {
        const unsigned u = fbits(x[j]);
        h[j] = (ushort_t)(u >> 16);
        l[j] = f2bf(x[j] - bitsf(u & 0xffff0000u));
    }
    *(short4*)&H[(size_t)i*4] = make_short4(h[0], h[1], h[2], h[3]);
    *(short4*)&L[(size_t)i*4] = make_short4(l[0], l[1], l[2], l[3]);
}

// -------------------------------------------------------------------------
// Kernel 3/5: split-bf16 MFMA GEMM (R9 structure, verified no-spill).
// 64x128xBK32 block tile, 32x64 wave tile. Q scale now 0.125*log2(e) so
// attention softmax runs in exp2 domain.
// -------------------------------------------------------------------------
template<int EPI>
__global__ __launch_bounds__(256)
void mfma_gemm_kernel(const ushort_t* __restrict__ Ath, const ushort_t* __restrict__ Atl,
                      const ushort_t* __restrict__ BTh, const ushort_t* __restrict__ BTl,
                      const float* __restrict__ bias,
                      float* __restrict__ O0,
                      ushort_t* __restrict__ Qhi, ushort_t* __restrict__ Qlo,
                      ushort_t* __restrict__ Khi, ushort_t* __restrict__ Klo,
                      ushort_t* __restrict__ Vthi, ushort_t* __restrict__ Vtlo,
                      int M, int N, int K)
{
    __shared__ __align__(16) char smem[34816];
    char* smAh = smem;             // [64][32] bf16 = 4 KB
    char* smAl = smem + 4096;
    char* smBh = smem + 8192;      // [128][32] bf16 = 8 KB
    char* smBl = smem + 16384;

    const int tid  = threadIdx.x;
    const int w    = tid >> 6;
    const int ln   = tid & 63;
    const int lx   = ln & 15;
    const int quad = ln >> 4;
    const int mw   = (w >> 1) * 32;
    const int nw   = (w & 1) * 64;
    const int m0   = blockIdx.y * 64;
    const int n0   = blockIdx.x * 128;

    const size_t gaA = (size_t)(m0 + w*16 + (ln >> 2))*K + (ln & 3)*8;
    const size_t gaB = (size_t)(n0 + w*32 + (ln >> 2))*K + (ln & 3)*8;
    const int ldsA = (w*64 + ln)*16;
    const int ldsB = (w*128 + ln)*16;

#define ISSUE_DMA(kk) do {                                               \
        dma16(Ath + gaA + (kk),        smAh + ldsA);                     \
        dma16(Atl + gaA + (kk),        smAl + ldsA);                     \
        dma16(BTh + gaB + (kk),        smBh + ldsB);                     \
        dma16(BTh + gaB + 16*K + (kk), smBh + ldsB + 1024);              \
        dma16(BTl + gaB + (kk),        smBl + ldsB);                     \
        dma16(BTl + gaB + 16*K + (kk), smBl + ldsB + 1024);              \
    } while (0)

    f32x4 acc[2][4];
#pragma unroll
    for (int mt = 0; mt < 2; ++mt)
#pragma unroll
        for (int nt = 0; nt < 4; ++nt) acc[mt][nt] = (f32x4){0.f,0.f,0.f,0.f};

    ISSUE_DMA(0);

    for (int kk = 0; kk < K; kk += 32) {
        __syncthreads();

        bf16x8 bfh[4], bfl[4];
#pragma unroll
        for (int nt = 0; nt < 4; ++nt) {
            const int off = (nw + nt*16 + lx)*64 + quad*16;
            bfh[nt] = *(const bf16x8*)(smBh + off);
            bfl[nt] = *(const bf16x8*)(smBl + off);
        }
        bf16x8 afh0, afl0, afh1, afl1;
        {
            const int o0 = (mw + lx)*64 + quad*16;
            const int o1 = (mw + 16 + lx)*64 + quad*16;
            afh0 = *(const bf16x8*)(smAh + o0);
            afl0 = *(const bf16x8*)(smAl + o0);
            afh1 = *(const bf16x8*)(smAh + o1);
            afl1 = *(const bf16x8*)(smAl + o1);
        }
        __syncthreads();
        if (kk + 32 < K) ISSUE_DMA(kk + 32);

#pragma unroll
        for (int nt = 0; nt < 4; ++nt) {
            acc[0][nt] = __builtin_amdgcn_mfma_f32_16x16x32_bf16(afh0, bfh[nt], acc[0][nt], 0, 0, 0);
            acc[0][nt] = __builtin_amdgcn_mfma_f32_16x16x32_bf16(afh0, bfl[nt], acc[0][nt], 0, 0, 0);
            acc[0][nt] = __builtin_amdgcn_mfma_f32_16x16x32_bf16(afl0, bfh[nt], acc[0][nt], 0, 0, 0);
        }
#pragma unroll
        for (int nt = 0; nt < 4; ++nt) {
            acc[1][nt] = __builtin_amdgcn_mfma_f32_16x16x32_bf16(afh1, bfh[nt], acc[1][nt], 0, 0, 0);
            acc[1][nt] = __builtin_amdgcn_mfma_f32_16x16x32_bf16(afh1, bfl[nt], acc[1][nt], 0, 0, 0);
            acc[1][nt] = __builtin_amdgcn_mfma_f32_16x16x32_bf16(afl1, bfh[nt], acc[1][nt], 0, 0, 0);
        }
    }
#undef ISSUE_DMA

    // ---------------- epilogue ----------------
    if (EPI == 0) {
#pragma unroll
        for (int nt = 0; nt < 4; ++nt) {
            const int n = n0 + nw + nt*16 + lx;
#pragma unroll
            for (int mt = 0; mt < 2; ++mt)
#pragma unroll
                for (int r = 0; r < 4; ++r) {
                    const int m = m0 + mw + mt*16 + quad*4 + r;
                    O0[(size_t)m*N + n] = acc[mt][nt][r] + bias[n];
                }
        }
    } else {
        const int which = n0 >> 10;           // block-uniform: 0=q 1=k 2=v
        const int hbase = (n0 & 1023) >> 6;
        const int b     = m0 >> 11;
        const int t0    = m0 & 2047;
        float* Ct = (float*)smem;             // Q/K: [64][132]; V: [128][68]
        const float ssign = (lx & 1) ? 1.0f : -1.0f;

        __syncthreads();
        if (which < 2) {
#pragma unroll
            for (int nt = 0; nt < 4; ++nt) {
                const int nl = nw + nt*16 + lx;
                const int d  = nl & 63;
                const float bn = bias[n0 + nl];
                const float freq = expf(-(float)(d >> 1) * 0.28782313662425575f);
#pragma unroll
                for (int mt = 0; mt < 2; ++mt)
#pragma unroll
                    for (int r = 0; r < 4; ++r) {
                        const int ml = mw + mt*16 + quad*4 + r;
                        const int t  = t0 + ml;
                        float res = acc[mt][nt][r] + bn;
                        const float ang = (float)t * freq;
                        const float sn = sinf(ang), cs = cosf(ang);
                        const float prt = __shfl_xor(res, 1);
                        res = res*cs + ssign*prt*sn;
                        // Q scale folds 1/sqrt(hd) AND log2(e): softmax in exp2 domain
                        if (which == 0) res *= 0.18033688011112042f;
                        Ct[ml*132 + nl] = res;
                    }
            }
        } else {
#pragma unroll
            for (int nt = 0; nt < 4; ++nt) {
                const int nl = nw + nt*16 + lx;
                const float bn = bias[n0 + nl];
#pragma unroll
                for (int mt = 0; mt < 2; ++mt)
#pragma unroll
                    for (int r = 0; r < 4; ++r) {
                        const int ml = mw + mt*16 + quad*4 + r;
                        Ct[nl*68 + ml] = acc[mt][nt][r] + bn;
                    }
            }
        }
        __syncthreads();

        if (which < 2) {
            ushort_t* dH = which ? Khi : Qhi;
            ushort_t* dL = which ? Klo : Qlo;
#pragma unroll
            for (int u = 0; u < 4; ++u) {
                const int L  = u*32 + (tid >> 3);
                const int t  = L & 63;
                const int hl = L >> 6;
                const int dg = (tid & 7) * 8;
                const float* src = &Ct[t*132 + hl*64 + dg];
                float v[8];
                *(f32x4*)&v[0] = *(const f32x4*)src;
                *(f32x4*)&v[4] = *(const f32x4*)(src + 4);
                bf16x8 h8, l8;
#pragma unroll
                for (int j = 0; j < 8; ++j) {
                    const unsigned u32 = fbits(v[j]);
                    h8[j] = (short)(u32 >> 16);
                    l8[j] = (short)f2bf(v[j] - bitsf(u32 & 0xffff0000u));
                }
                const int bh = b*NH + hbase + hl;
                const size_t off = (((size_t)bh)*T_SEQ + t0 + t)*64 + dg;
                *(bf16x8*)&dH[off] = h8;
                *(bf16x8*)&dL[off] = l8;
            }
        } else {
#pragma unroll
            for (int u = 0; u < 4; ++u) {
                const int row = u*32 + (tid >> 3);
                const int d   = row & 63;
                const int hl  = row >> 6;
                const int tg  = (tid & 7) * 8;
                const float* src = &Ct[row*68 + tg];
                float v[8];
                *(f32x4*)&v[0] = *(const f32x4*)src;
                *(f32x4*)&v[4] = *(const f32x4*)(src + 4);
                bf16x8 h8, l8;
#pragma unroll
                for (int j = 0; j < 8; ++j) {
                    const unsigned u32 = fbits(v[j]);
                    h8[j] = (short)(u32 >> 16);
                    l8[j] = (short)f2bf(v[j] - bitsf(u32 & 0xffff0000u));
                }
                const int bh = b*NH + hbase + hl;
                const size_t off = (((size_t)bh)*HD + d)*T_SEQ + t0 + tg;
                *(bf16x8*)&Vthi[off] = h8;
                *(bf16x8*)&Vtlo[off] = l8;
            }
        }
    }
}

// -------------------------------------------------------------------------
// Kernel 4: flash attention. 512 threads (8 waves share one K/V LDS tile
// set -> 2 blocks/CU = 16 waves/CU), exp2-domain softmax (scale folded
// into Q), epilogue emits AOh/AOl bf16 hi/lo directly.
// -------------------------------------------------------------------------
__global__ __launch_bounds__(512)
void attn_mfma_kernel(const ushort_t* __restrict__ Qhi, const ushort_t* __restrict__ Qlo,
                      const ushort_t* __restrict__ Khi, const ushort_t* __restrict__ Klo,
                      const ushort_t* __restrict__ Vthi, const ushort_t* __restrict__ Vtlo,
                      const float* __restrict__ valid,
                      ushort_t* __restrict__ AOh, ushort_t* __restrict__ AOl)
{
    __shared__ ushort_t KH[64*64];
    __shared__ ushort_t KL[64*64];
    __shared__ ushort_t VH[64*64];
    __shared__ ushort_t VL[64*64];
    __shared__ float Pb[8][16][68];

    const int tid  = threadIdx.x;
    const int w    = tid >> 6;          // 0..7
    const int ln   = tid & 63;
    const int lx   = ln & 15;
    const int quad = ln >> 4;

    // 1024 blocks: id&7 = bh low bits (XCD), (id>>3)&15 = qt, id>>7 = bh hi
    const int id = blockIdx.x;
    const int qt = (id >> 3) & 15;
    const int bh = ((id >> 7) << 3) | (id & 7);
    const int b  = bh >> 4;
    const int h  = bh & 15;
    const int qrow0 = qt*128 + w*16;

    bf16x8 qh[2], ql[2];
    {
        const size_t qoff = (((size_t)bh)*T_SEQ + qrow0 + lx)*HD + quad*8;
        qh[0] = *(const bf16x8*)&Qhi[qoff];
        qh[1] = *(const bf16x8*)&Qhi[qoff + 32];
        ql[0] = *(const bf16x8*)&Qlo[qoff];
        ql[1] = *(const bf16x8*)&Qlo[qoff + 32];
    }

    // staging: wave w stages rows [w*8, w*8+8); lane ln -> row w*8+(ln>>3),
    // chunk ln&7; one instruction per array per wave.
    const int srow = w*8 + (ln >> 3);
    const int sch  = ln & 7;
    const size_t kg0 = ((size_t)bh*T_SEQ + srow)*HD + sch*8;
    const size_t vg0 = ((size_t)bh*HD + srow)*T_SEQ + sch*8;
    const int lw = srow*64 + ((sch ^ (srow & 7)) * 8);

    const float* vrow = valid + (size_t)b*T_SEQ + lx;

    f32x4 o[4];
#pragma unroll
    for (int nt = 0; nt < 4; ++nt) o[nt] = (f32x4){0.f, 0.f, 0.f, 0.f};
    float mrow[4] = {-INFINITY, -INFINITY, -INFINITY, -INFINITY};
    float lrow[4] = {0.f, 0.f, 0.f, 0.f};

    bf16x8 rkh, rkl, rvh, rvl;
    rkh = *(const bf16x8*)&Khi [kg0];
    rkl = *(const bf16x8*)&Klo [kg0];
    rvh = *(const bf16x8*)&Vthi[vg0];
    rvl = *(const bf16x8*)&Vtlo[vg0];
    *(bf16x8*)&KH[lw] = rkh;
    *(bf16x8*)&KL[lw] = rkl;
    *(bf16x8*)&VH[lw] = rvh;
    *(bf16x8*)&VL[lw] = rvl;
    __syncthreads();

    for (int kt = 0; kt < T_SEQ/64; ++kt) {
        const int ktn = (kt+1 < T_SEQ/64) ? kt+1 : kt;
        rkh = *(const bf16x8*)&Khi [kg0 + (size_t)ktn*64*HD];
        rkl = *(const bf16x8*)&Klo [kg0 + (size_t)ktn*64*HD];
        rvh = *(const bf16x8*)&Vthi[vg0 + ktn*64];
        rvl = *(const bf16x8*)&Vtlo[vg0 + ktn*64];
        float mk[4];
#pragma unroll
        for (int nt = 0; nt < 4; ++nt) mk[nt] = vrow[kt*64 + nt*16];

        f32x4 s[4];
#pragma unroll
        for (int nt = 0; nt < 4; ++nt) {
            const int base = (nt*16 + lx)*64;
            const int sw = lx & 7;
            const int c0 = ((0*4 + quad) ^ sw) * 8;
            const int c1 = ((1*4 + quad) ^ sw) * 8;
            const bf16x8 kh0 = *(const bf16x8*)&KH[base + c0];
            const bf16x8 kh1 = *(const bf16x8*)&KH[base + c1];
            const bf16x8 kl0 = *(const bf16x8*)&KL[base + c0];
            const bf16x8 kl1 = *(const bf16x8*)&KL[base + c1];
            s[nt] = (f32x4){0.f, 0.f, 0.f, 0.f};
            s[nt] = __builtin_amdgcn_mfma_f32_16x16x32_bf16(qh[0], kh0, s[nt], 0, 0, 0);
            s[nt] = __builtin_amdgcn_mfma_f32_16x16x32_bf16(qh[1], kh1, s[nt], 0, 0, 0);
            s[nt] = __builtin_amdgcn_mfma_f32_16x16x32_bf16(ql[0], kh0, s[nt], 0, 0, 0);
            s[nt] = __builtin_amdgcn_mfma_f32_16x16x32_bf16(ql[1], kh1, s[nt], 0, 0, 0);
            s[nt] = __builtin_amdgcn_mfma_f32_16x16x32_bf16(qh[0], kl0, s[nt], 0, 0, 0);
            s[nt] = __builtin_amdgcn_mfma_f32_16x16x32_bf16(qh[1], kl1, s[nt], 0, 0, 0);
        }

#pragma unroll
        for (int nt = 0; nt < 4; ++nt) {
            const bool ok = mk[nt] > 0.5f;
#pragma unroll
            for (int r = 0; r < 4; ++r) s[nt][r] = ok ? s[nt][r] : -1e30f;
        }

        // online softmax in exp2 domain (Q pre-scaled by 0.125*log2e)
        float alpha[4], mnew[4];
#pragma unroll
        for (int r = 0; r < 4; ++r) {
            float mt = fmaxf(fmaxf(s[0][r], s[1][r]), fmaxf(s[2][r], s[3][r]));
            mt = fmaxf(mt, __shfl_xor(mt, 1));
            mt = fmaxf(mt, __shfl_xor(mt, 2));
            mt = fmaxf(mt, __shfl_xor(mt, 4));
            mt = fmaxf(mt, __shfl_xor(mt, 8));
            mnew[r]  = fmaxf(mrow[r], mt);
            alpha[r] = exp2_raw(mrow[r] - mnew[r]);
            mrow[r]  = mnew[r];
        }
        float p[4][4];
#pragma unroll
        for (int r = 0; r < 4; ++r) {
            float lt = 0.f;
#pragma unroll
            for (int nt = 0; nt < 4; ++nt) { p[nt][r] = exp2_raw(s[nt][r] - mnew[r]); lt += p[nt][r]; }
            lt += __shfl_xor(lt, 1);
            lt += __shfl_xor(lt, 2);
            lt += __shfl_xor(lt, 4);
            lt += __shfl_xor(lt, 8);
            lrow[r] = lrow[r]*alpha[r] + lt;
#pragma unroll
            for (int nt = 0; nt < 4; ++nt) o[nt][r] *= alpha[r];
        }

#pragma unroll
        for (int nt = 0; nt < 4; ++nt)
#pragma unroll
            for (int r = 0; r < 4; ++r)
                Pb[w][quad*4 + r][nt*16 + lx] = p[nt][r];

        bf16x8 ph[2], pl[2];
#pragma unroll
        for (int ks = 0; ks < 2; ++ks) {
            float pv[8];
            *(f32x4*)&pv[0] = *(const f32x4*)&Pb[w][lx][ks*32 + quad*8];
            *(f32x4*)&pv[4] = *(const f32x4*)&Pb[w][lx][ks*32 + quad*8 + 4];
#pragma unroll
            for (int j = 0; j < 8; ++j) {
                const unsigned ub = fbits(pv[j]);
                ph[ks][j] = (short)(ub >> 16);
                const float lof = pv[j] - bitsf(ub & 0xffff0000u);
                pl[ks][j] = (short)(fbits(lof) >> 16);
            }
        }

#pragma unroll
        for (int nt = 0; nt < 4; ++nt) {
            const int base = (nt*16 + lx)*64;
            const int sw = lx & 7;
            const int c0 = ((0*4 + quad) ^ sw) * 8;
            const int c1 = ((1*4 + quad) ^ sw) * 8;
            const bf16x8 vh0 = *(const bf16x8*)&VH[base + c0];
            const bf16x8 vh1 = *(const bf16x8*)&VH[base + c1];
            const bf16x8 vl0 = *(const bf16x8*)&VL[base + c0];
            const bf16x8 vl1 = *(const bf16x8*)&VL[base + c1];
            o[nt] = __builtin_amdgcn_mfma_f32_16x16x32_bf16(ph[0], vh0, o[nt], 0, 0, 0);
            o[nt] = __builtin_amdgcn_mfma_f32_16x16x32_bf16(ph[1], vh1, o[nt], 0, 0, 0);
            o[nt] = __builtin_amdgcn_mfma_f32_16x16x32_bf16(pl[0], vh0, o[nt], 0, 0, 0);
            o[nt] = __builtin_amdgcn_mfma_f32_16x16x32_bf16(pl[1], vh1, o[nt], 0, 0, 0);
            o[nt] = __builtin_amdgcn_mfma_f32_16x16x32_bf16(ph[0], vl0, o[nt], 0, 0, 0);
            o[nt] = __builtin_amdgcn_mfma_f32_16x16x32_bf16(ph[1], vl1, o[nt], 0, 0, 0);
        }

        __syncthreads();
        *(bf16x8*)&KH[lw] = rkh;
        *(bf16x8*)&KL[lw] = rkl;
        *(bf16x8*)&VH[lw] = rvh;
        *(bf16x8*)&VL[lw] = rvl;
        __syncthreads();
    }

    // ---- normalize + fused bf16 hi/lo store to AOh/AOl[b][t][h*64+dv] ----
    float inv[4];
#pragma unroll
    for (int r = 0; r < 4; ++r) inv[r] = 1.0f / lrow[r];
#pragma unroll
    for (int nt = 0; nt < 4; ++nt)
#pragma unroll
        for (int r = 0; r < 4; ++r) {
            const int t = qrow0 + quad*4 + r;
            const float res = o[nt][r] * inv[r];
            const unsigned u32 = fbits(res);
            const size_t off = (((size_t)b)*T_SEQ + t)*DM + h*HD + nt*16 + lx;
            AOh[off] = (ushort_t)(u32 >> 16);
            AOl[off] = f2bf(res - bitsf(u32 & 0xffff0000u));
        }
}

// -------------------------------------------------------------------------
// Memory plan: d_ws 128.03 MiB + d_out as scratch.
//   d_ws: Qhi Qlo Khi Klo Vthi Vtlo (6x16 MiB) | MSK 32 KiB |
//         32-MiB region: WqkvTh/Tl (12 MiB, dead after QKV GEMM) then
//         AOh/AOl (2x16 MiB, written by attention epilogue)
//   d_out: TokH/TokL (32 MiB) — dead after QKV GEMM
//   WoutTh/Tl <- Khi region (dead after attention)
// -------------------------------------------------------------------------
extern "C" void kernel_launch(void* const* d_in, const int* in_sizes, int n_in,
                              void* d_out, int out_size, void* d_ws, size_t ws_size,
                              hipStream_t stream)
{
    const float* tokens = (const float*)d_in[0];
    const int*   pad    = (const int*)d_in[1];
    const float* Wqkv   = (const float*)d_in[2];
    const float* bqkv   = (const float*)d_in[3];
    const float* Wout   = (const float*)d_in[4];
    const float* bout   = (const float*)d_in[5];
    float* out = (float*)d_out;

    const size_t SZ = (size_t)8388608;
    ushort_t* U = (ushort_t*)d_ws;
    ushort_t* Qhi  = U;
    ushort_t* Qlo  = U + SZ;
    ushort_t* Khi  = U + 2*SZ;
    ushort_t* Klo  = U + 3*SZ;
    ushort_t* Vthi = U + 4*SZ;
    ushort_t* Vtlo = U + 5*SZ;
    float* MSK = (float*)(U + 6*SZ);
    ushort_t* R   = (ushort_t*)(MSK + 8192);       // 32-MiB region
    ushort_t* WqkvTh = R;
    ushort_t* WqkvTl = R + (size_t)3*DM*DM;
    ushort_t* AOh = R;                             // overlays dead WqkvT
    ushort_t* AOl = R + SZ;
    ushort_t* TokH = (ushort_t*)d_out;             // scratch in d_out
    ushort_t* TokL = TokH + SZ;
    ushort_t* WoutTh = Khi;                        // dead after attention
    ushort_t* WoutTl = Khi + (size_t)DM*DM;

    maskprep_kernel<<<dim3(BATCH), dim3(256), 0, stream>>>(pad, MSK);
    split_kernel<<<dim3(8192), dim3(256), 0, stream>>>(tokens, TokH, TokL);
    transpose_split_kernel<<<dim3(48, 16), dim3(256), 0, stream>>>(
        Wqkv, WqkvTh, WqkvTl, DM, 3*DM);
    mfma_gemm_kernel<1><<<dim3(24, 128), dim3(256), 0, stream>>>(
        TokH, TokL, WqkvTh, WqkvTl, bqkv, nullptr,
        Qhi, Qlo, Khi, Klo, Vthi, Vtlo, BATCH*T_SEQ, 3*DM, DM);
    attn_mfma_kernel<<<dim3(1024), dim3(512), 0, stream>>>(
        Qhi, Qlo, Khi, Klo, Vthi, Vtlo, MSK, AOh, AOl);
    transpose_split_kernel<<<dim3(16, 16), dim3(256), 0, stream>>>(
        Wout, WoutTh, WoutTl, DM, DM);
    mfma_gemm_kernel<0><<<dim3(8, 128), dim3(256), 0, stream>>>(
        AOh, AOl, WoutTh, WoutTl, bout, out,
        nullptr, nullptr, nullptr, nullptr, nullptr, nullptr, BATCH*T_SEQ, DM, DM);
}